// Round 10
// baseline (315.039 us; speedup 1.0000x reference)
//
#include <hip/hip_runtime.h>

typedef unsigned int u32;
typedef unsigned long long u64;
typedef __bf16 bf16x8 __attribute__((ext_vector_type(8)));
typedef float f32x4 __attribute__((ext_vector_type(4)));

// Problem constants
#define N_PIX   32768        // 8*64*64 pixels
#define C_DIM   64
#define NE      8192
#define HW      4096         // 64*64
#define BHW     262144       // elements per batch in z (64*4096)
#define ZQ_N    2097152      // 8*64*64*64

// Output layout (flat f32): [0]=loss, [1..2097152]=z_q_out(NCHW), [2097153..]=idx
#define OUT_ZQ_OFF  1
#define OUT_IDX_OFF (1 + ZQ_N)

// Scratch inside d_out's zq region (overwritten by k_final at the end).
// SCR = out + 4 floats (16B aligned). Offsets in 4-byte slots relative to SCR:
#define OFF_ZH     0         // u32[1048576]  : zh bf16 pairs, [pixel][feat]
#define OFF_EH     1048576   // u32[262144]   : eh bf16 pairs, [code][feat]
#define OFF_S      1310720   // f32[32768]    : ||z||^2 exact pairwise
#define OFF_W      1343488   // f32[32768]    : refine window per pixel
#define OFF_CMIN16 1376256   // u32[16*32768] : per-slice order-encoded coarse min
#define OFF_LIST   1900544   // u32[CAP]      : candidate (pixel<<13|code)
#define CAP        196096

// Workspace (ws) layout:
#define WS_E_OFF  262144   // f32 Etab[8192] after u64 best[32768]
#define WS_C_OFF  294912   // u32 count
#define WS_D_OFF  294916   // u32 done (k_final last-block counter)
#define WS_A_OFF  294920   // f64 loss_acc

// GEMM tiling: SINGLE-WAVE blocks (round-9 lesson: compiler pins VGPR~52 and
// remats A-loads; latency must be covered by TLP). Wave = 64 pixel-rows x
// 512 codes; grid = 512 row-blocks x 16 slices = 8192 waves = 8/SIMD.
#define M_BLK    64
#define N_SLICE  512
#define N_SLICES 16        // NE / N_SLICE
#define LOCBUF   512       // per-block candidate staging (expected ~6/block)

__device__ __forceinline__ u32 encf(float v) {
    u32 u = __float_as_uint(v);
    return (u & 0x80000000u) ? ~u : (u | 0x80000000u);
}
__device__ __forceinline__ float decf(u32 k) {
    return (k & 0x80000000u) ? __uint_as_float(k ^ 0x80000000u)
                             : __uint_as_float(~k);
}
__device__ __forceinline__ u32 bf16rn(float v) {      // RNE f32->bf16 bits
    u32 u = __float_as_uint(v);
    return (u + 0x7FFFu + ((u >> 16) & 1u)) >> 16;
}

// Fused prep: blocks [0,128) process z (pixels), blocks [128,160) process emb.
// z-part also does all one-time inits (best, count/done/loss_acc).
__global__ __launch_bounds__(256) void k_prep(const float* __restrict__ z,
                                              const float* __restrict__ emb,
                                              u32* __restrict__ zh,
                                              u32* __restrict__ eh,
                                              float* __restrict__ Sarr,
                                              float* __restrict__ Wp,
                                              float* __restrict__ Etab,
                                              u64* __restrict__ best,
                                              u32* __restrict__ count,
                                              u32* __restrict__ done,
                                              double* __restrict__ loss_acc) {
    __shared__ u32 lw[256 * 33];
    const int tid = threadIdx.x;
    if (blockIdx.x < N_PIX / 256) {
        const int p = blockIdx.x * 256 + tid;
        best[p] = ~0ull;
        if (blockIdx.x == 0 && tid == 0) { *count = 0u; *done = 0u; *loss_acc = 0.0; }
        const float* zp = z + (p >> 12) * BHW + (p & 4095);
        float r[8]; float asum = 0.0f; u32 prev = 0;
#pragma unroll
        for (int c = 0; c < C_DIM; ++c) {
            float v  = zp[c * HW];                    // coalesced
            float sq = __fmul_rn(v, v);
            if (c < 8) r[c] = sq; else r[c & 7] = __fadd_rn(r[c & 7], sq);
            asum += fabsf(v);
            u32 hb = bf16rn(v);
            if (c & 1) lw[tid * 33 + (c >> 1)] = prev | (hb << 16);
            else       prev = hb;
        }
        Sarr[p] = __fadd_rn(__fadd_rn(__fadd_rn(r[0], r[1]), __fadd_rn(r[2], r[3])),
                            __fadd_rn(__fadd_rn(r[4], r[5]), __fadd_rn(r[6], r[7])));
        // window: bf16-dot bound (slope 3x margin) + E_max(6.4e-5) + ref-rounding
        Wp[p] = 5.0e-5f * asum + 2.5e-4f;
        __syncthreads();
#pragma unroll
        for (int j = 0; j < 32; ++j) {                // coalesced u32 writes
            int lg = j * 256 + tid;
            zh[blockIdx.x * 8192 + lg] = lw[(lg >> 5) * 33 + (lg & 31)];
        }
    } else {
        const int mb = blockIdx.x - N_PIX / 256;
        const int m  = mb * 256 + tid;
        const float* rp = emb + m * C_DIM;
        float r[8]; u32 prev = 0;
#pragma unroll
        for (int c = 0; c < C_DIM; ++c) {
            float v  = rp[c];
            float sq = __fmul_rn(v, v);
            if (c < 8) r[c] = sq; else r[c & 7] = __fadd_rn(r[c & 7], sq);
            u32 hb = bf16rn(v);
            if (c & 1) lw[tid * 33 + (c >> 1)] = prev | (hb << 16);
            else       prev = hb;
        }
        Etab[m] = __fadd_rn(__fadd_rn(__fadd_rn(r[0], r[1]), __fadd_rn(r[2], r[3])),
                            __fadd_rn(__fadd_rn(r[4], r[5]), __fadd_rn(r[6], r[7])));
        __syncthreads();
#pragma unroll
        for (int j = 0; j < 32; ++j) {
            int lg = j * 256 + tid;
            eh[mb * 8192 + lg] = lw[(lg >> 5) * 33 + (lg & 31)];
        }
    }
}

// Coarse GEMM, single-wave blocks. Score = acc = zh.eh (bf16 MFMA);
// min dist <=> max acc (||e||^2 absorbed into Wp). A fragments loaded
// directly global->VGPR; B depth-2 named ping-pong (round-8 scratch lesson).
// PASS 0: per-row max over the wave's 512 codes -> shfl-reduce -> PLAIN
//         store to cmin16[slice][row] (wave owns its rows exclusively).
// PASS 1: thr = decf(min16 of cmin16) + Wp; collect acc >= -thr/2 via LDS
//         staging, one global ticket per block (round-4 lesson).
#define GEMM_STEP(CG, B0, B1)                                                   \
    {                                                                           \
        _Pragma("unroll")                                                       \
        for (int rt = 0; rt < 4; ++rt) {                                        \
            f32x4 acc = {0.f, 0.f, 0.f, 0.f};                                   \
            acc = __builtin_amdgcn_mfma_f32_16x16x32_bf16(af[rt][0], B0, acc, 0, 0, 0); \
            acc = __builtin_amdgcn_mfma_f32_16x16x32_bf16(af[rt][1], B1, acc, 0, 0, 0); \
            _Pragma("unroll")                                                   \
            for (int rg = 0; rg < 4; ++rg) {                                    \
                if (PASS == 0) {                                                \
                    vmax[rt * 4 + rg] = fmaxf(vmax[rt * 4 + rg], acc[rg]);      \
                } else {                                                        \
                    if (acc[rg] >= nthr[rt * 4 + rg]) {                         \
                        int pixel = pixbase + rt * 16 + q * 4 + rg;             \
                        int code  = code0 + (CG) * 16 + c15;                    \
                        u32 entry = ((u32)pixel << 13) | (u32)code;             \
                        u32 pos = atomicAdd(&loc_cnt, 1u);                      \
                        if (pos < LOCBUF) loc_list[pos] = entry;                \
                        else { u32 g = atomicAdd(count, 1u);                    \
                               if (g < CAP) list[g] = entry; }                  \
                    }                                                           \
                }                                                               \
            }                                                                   \
        }                                                                       \
    }

template <int PASS>
__global__ __launch_bounds__(64)
void k_gemm(const bf16x8* __restrict__ zh8,
            const bf16x8* __restrict__ eh8,
            const float* __restrict__ Wp,
            u32* __restrict__ cmin16,
            u32* __restrict__ count,
            u32* __restrict__ list) {
    __shared__ float thr_l[M_BLK];       // pass-1 raw thresholds
    __shared__ u32 loc_list[LOCBUF];     // 2 KB pass-1 candidate staging
    __shared__ u32 loc_cnt, glob_base;

    const int tid  = threadIdx.x;        // == lane (single wave)
    const int q = tid >> 4, c15 = tid & 15;
    const int pixbase = blockIdx.x * M_BLK;
    const int code0   = blockIdx.y * N_SLICE;

    // B prefetch (named vars only), issued first.
    const bf16x8* bpl = eh8 + (size_t)(code0 + c15) * 8 + q;
    bf16x8 n0a = bpl[0],   n1a = bpl[4];      // cg+0
    bf16x8 n0b = bpl[128], n1b = bpl[132];    // cg+1

    // A fragments straight from global (L2-hot, 8 x 16B per thread).
    const bf16x8* apl = zh8 + (size_t)(pixbase + c15) * 8 + q;
    bf16x8 af[4][2];
#pragma unroll
    for (int rt = 0; rt < 4; ++rt) {
        af[rt][0] = apl[rt * 128];
        af[rt][1] = apl[rt * 128 + 4];
    }

    if (PASS == 1) {
        // threshold for this block's 64 pixels: min over the 16 slice-mins
        u32 mn = 0xFFFFFFFFu;
#pragma unroll
        for (int s = 0; s < N_SLICES; ++s)
            mn = min(mn, cmin16[s * N_PIX + pixbase + tid]);  // encoded: u32 min ok
        thr_l[tid] = decf(mn) + Wp[pixbase + tid];
        if (tid == 0) loc_cnt = 0u;
        __syncthreads();                 // 1-wave barrier: cheap
    }

    float vmax[16];
    float nthr[16];
#pragma unroll
    for (int i = 0; i < 16; ++i) vmax[i] = -3.402823466e38f;
    if (PASS == 1) {
#pragma unroll
        for (int rt = 0; rt < 4; ++rt)
#pragma unroll
            for (int rg = 0; rg < 4; ++rg)   // acc >= -thr/2  <=>  -2acc <= thr
                nthr[rt * 4 + rg] = -0.5f * thr_l[rt * 16 + q * 4 + rg];
    }

    // 512 codes, barrier-free, depth-2 ping-pong.
#pragma unroll 2
    for (int cg = 0; cg < 32; cg += 2) {
        bf16x8 c0 = n0a, c1 = n1a;
        if (cg + 2 < 32) { n0a = bpl[(cg + 2) * 128]; n1a = bpl[(cg + 2) * 128 + 4]; }
        GEMM_STEP(cg, c0, c1);
        bf16x8 d0 = n0b, d1 = n1b;
        if (cg + 3 < 32) { n0b = bpl[(cg + 3) * 128]; n1b = bpl[(cg + 3) * 128 + 4]; }
        GEMM_STEP(cg + 1, d0, d1);
    }

    if (PASS == 0) {
        // Reduce the 16 code-columns per row; wave owns its rows -> plain store.
#pragma unroll
        for (int i = 0; i < 16; ++i) {
            float v = vmax[i];
            v = fmaxf(v, __shfl_xor(v, 1));
            v = fmaxf(v, __shfl_xor(v, 2));
            v = fmaxf(v, __shfl_xor(v, 4));
            v = fmaxf(v, __shfl_xor(v, 8));
            if (c15 == 0) {
                int row = (i >> 2) * 16 + q * 4 + (i & 3);
                cmin16[blockIdx.y * N_PIX + pixbase + row] = encf(-2.0f * v);
            }
        }
    } else {
        // Block-level flush: one global ticket, coalesced list writes.
        __syncthreads();
        u32 n_loc = loc_cnt; if (n_loc > LOCBUF) n_loc = LOCBUF;
        if (tid == 0) glob_base = atomicAdd(count, n_loc);
        __syncthreads();
        u32 base = glob_base;
        for (u32 i = tid; i < n_loc; i += 64u) {
            u32 g = base + i;
            if (g < CAP) list[g] = loc_list[i];
        }
    }
}

// Exact refine: bit-identical reference distance chain per candidate pair.
__global__ __launch_bounds__(256) void k_refine(const float* __restrict__ z,
                                                const float* __restrict__ emb,
                                                const float* __restrict__ Sarr,
                                                const float* __restrict__ Etab,
                                                const u32* __restrict__ count,
                                                const u32* __restrict__ list,
                                                u64* __restrict__ best) {
    u32 cnt = *count; if (cnt > CAP) cnt = CAP;
    for (u32 i = blockIdx.x * 256 + threadIdx.x; i < cnt; i += 256u * 256u) {
        u32 e = list[i];
        int pixel = (int)(e >> 13), code = (int)(e & 8191u);
        const float* zp = z + (pixel >> 12) * BHW + (pixel & 4095);
        const float* ep = emb + code * C_DIM;
        float dot = 0.0f;
#pragma unroll
        for (int c = 0; c < C_DIM; ++c)
            dot = __builtin_fmaf(zp[c * HW], ep[c], dot);
        float dist = __fsub_rn(__fadd_rn(Sarr[pixel], Etab[code]),
                               __fmul_rn(2.0f, dot));
        u64 key = ((u64)__float_as_uint(dist) << 32) | (u32)code;  // dist > 0
        atomicMin(&best[pixel], key);
    }
}

// Gather z_q, write idx + z_q_st (NCHW); f64 loss via global atomicAdd,
// last-finishing block (done-counter) writes out[0].
__global__ __launch_bounds__(256) void k_final(const float* __restrict__ z,
                                               const float* __restrict__ emb,
                                               const u64* __restrict__ best,
                                               float* __restrict__ out,
                                               double* __restrict__ loss_acc,
                                               u32* __restrict__ done) {
    const int n  = blockIdx.x * 256 + threadIdx.x;
    const int b  = n >> 12;
    const int hw = n & 4095;
    const u32 m  = (u32)(best[n] & 0xFFFFFFFFull);
    out[OUT_IDX_OFF + n] = (float)m;

    const float* zp = z + b * BHW + hw;
    const float* e  = emb + m * C_DIM;
    double lacc = 0.0;
#pragma unroll
    for (int c = 0; c < 64; ++c) {
        float zz   = zp[c * HW];
        float ec   = e[c];
        float diff = __fsub_rn(ec, zz);
        float outv = __fadd_rn(zz, diff);
        out[OUT_ZQ_OFF + b * BHW + c * HW + hw] = outv;
        lacc += (double)__fmul_rn(diff, diff);
    }
    __shared__ double sh[256];
    sh[threadIdx.x] = lacc;
    __syncthreads();
#pragma unroll
    for (int s = 128; s > 0; s >>= 1) {
        if (threadIdx.x < s) sh[threadIdx.x] += sh[threadIdx.x + s];
        __syncthreads();
    }
    if (threadIdx.x == 0) {
        atomicAdd(loss_acc, sh[0]);                 // device-scope f64 add
        __threadfence();
        u32 d = atomicAdd(done, 1u);
        if (d == (N_PIX / 256) - 1) {               // last block
            double s = atomicAdd(loss_acc, 0.0);    // atomic read of full sum
            float m1 = (float)(s / (double)ZQ_N);
            out[0] = __fadd_rn(m1, __fmul_rn(0.25f, m1));
        }
    }
}

extern "C" void kernel_launch(void* const* d_in, const int* in_sizes, int n_in,
                              void* d_out, int out_size, void* d_ws, size_t ws_size,
                              hipStream_t stream) {
    const float* z   = (const float*)d_in[0];
    const float* emb = (const float*)d_in[1];
    float* out = (float*)d_out;

    char* ws = (char*)d_ws;
    u64*    best  = (u64*)ws;
    float*  Etab  = (float*)(ws + WS_E_OFF);
    u32*    count = (u32*)(ws + WS_C_OFF);
    u32*    done  = (u32*)(ws + WS_D_OFF);
    double* lacc  = (double*)(ws + WS_A_OFF);

    float* SCR = out + 4;                       // 16B-aligned scratch in zq region
    u32*   zh     = (u32*)(SCR + OFF_ZH);
    u32*   eh     = (u32*)(SCR + OFF_EH);
    float* Sarr   = SCR + OFF_S;
    float* Wp     = SCR + OFF_W;
    u32*   cmin16 = (u32*)(SCR + OFF_CMIN16);
    u32*   list   = (u32*)(SCR + OFF_LIST);

    k_prep<<<dim3(N_PIX / 256 + NE / 256), dim3(256), 0, stream>>>(
        z, emb, zh, eh, Sarr, Wp, Etab, best, count, done, lacc);
    k_gemm<0><<<dim3(N_PIX / M_BLK, N_SLICES), dim3(64), 0, stream>>>(
        (const bf16x8*)zh, (const bf16x8*)eh, Wp, cmin16, count, list);
    k_gemm<1><<<dim3(N_PIX / M_BLK, N_SLICES), dim3(64), 0, stream>>>(
        (const bf16x8*)zh, (const bf16x8*)eh, Wp, cmin16, count, list);
    k_refine<<<dim3(256), dim3(256), 0, stream>>>(z, emb, Sarr, Etab, count, list, best);
    k_final <<<dim3(N_PIX / 256), dim3(256), 0, stream>>>(z, emb, best, out, lacc, done);
}

// Round 11
// 247.621 us; speedup vs baseline: 1.2723x; 1.2723x over previous
//
#include <hip/hip_runtime.h>

typedef unsigned int u32;
typedef unsigned long long u64;
typedef __bf16 bf16x8 __attribute__((ext_vector_type(8)));
typedef float f32x4 __attribute__((ext_vector_type(4)));

// Problem constants
#define N_PIX   32768        // 8*64*64 pixels
#define C_DIM   64
#define NE      8192
#define HW      4096         // 64*64
#define BHW     262144       // elements per batch in z (64*4096)
#define ZQ_N    2097152      // 8*64*64*64

// Output layout (flat f32): [0]=loss, [1..2097152]=z_q_out(NCHW), [2097153..]=idx
#define OUT_ZQ_OFF  1
#define OUT_IDX_OFF (1 + ZQ_N)

// Scratch inside d_out's zq region (overwritten by k_final at the end).
// SCR = out + 4 floats (16B aligned). Offsets in 4-byte slots relative to SCR:
#define OFF_ZH    0         // u32[1048576]  : zh bf16 pairs, [pixel][feat]
#define OFF_EH    1048576   // u32[262144]   : eh bf16 pairs, [code][feat]
#define OFF_S     1310720   // f32[32768]    : ||z||^2 exact pairwise
#define OFF_W     1343488   // f32[32768]    : refine window per pixel
#define OFF_CMIN8 1376256   // u32[8*32768]  : per-slice order-encoded coarse min
#define OFF_LIST  1638400   // u32[CAP]      : candidate (pixel<<13|code)
#define CAP       458744

// Workspace (ws) layout:
#define WS_E_OFF  262144   // f32 Etab[8192] after u64 best[32768]
#define WS_C_OFF  294912   // u32 count
#define WS_D_OFF  294916   // u32 done (k_final last-block counter)
#define WS_A_OFF  294920   // f64 loss_acc

// GEMM tiling (round-9 best shape): block = 256 thr = 4 waves =
// 2 row-groups x 2 code-groups. Wave = 64 pixel-rows x 512 codes from L2.
#define M_BLK    128
#define N_SLICE  1024
#define N_SLICES 8         // NE / N_SLICE
#define LOCBUF   1024      // per-block candidate staging (expected ~30/block)

__device__ __forceinline__ u32 encf(float v) {
    u32 u = __float_as_uint(v);
    return (u & 0x80000000u) ? ~u : (u | 0x80000000u);
}
__device__ __forceinline__ float decf(u32 k) {
    return (k & 0x80000000u) ? __uint_as_float(k ^ 0x80000000u)
                             : __uint_as_float(~k);
}
__device__ __forceinline__ u32 bf16rn(float v) {      // RNE f32->bf16 bits
    u32 u = __float_as_uint(v);
    return (u + 0x7FFFu + ((u >> 16) & 1u)) >> 16;
}

// Fused prep: blocks [0,128) process z (pixels), blocks [128,160) process emb.
// z-part also does all one-time inits (best, count/done/loss_acc).
__global__ __launch_bounds__(256) void k_prep(const float* __restrict__ z,
                                              const float* __restrict__ emb,
                                              u32* __restrict__ zh,
                                              u32* __restrict__ eh,
                                              float* __restrict__ Sarr,
                                              float* __restrict__ Wp,
                                              float* __restrict__ Etab,
                                              u64* __restrict__ best,
                                              u32* __restrict__ count,
                                              u32* __restrict__ done,
                                              double* __restrict__ loss_acc) {
    __shared__ u32 lw[256 * 33];
    const int tid = threadIdx.x;
    if (blockIdx.x < N_PIX / 256) {
        const int p = blockIdx.x * 256 + tid;
        best[p] = ~0ull;
        if (blockIdx.x == 0 && tid == 0) { *count = 0u; *done = 0u; *loss_acc = 0.0; }
        const float* zp = z + (p >> 12) * BHW + (p & 4095);
        float r[8]; float asum = 0.0f; u32 prev = 0;
#pragma unroll
        for (int c = 0; c < C_DIM; ++c) {
            float v  = zp[c * HW];                    // coalesced
            float sq = __fmul_rn(v, v);
            if (c < 8) r[c] = sq; else r[c & 7] = __fadd_rn(r[c & 7], sq);
            asum += fabsf(v);
            u32 hb = bf16rn(v);
            if (c & 1) lw[tid * 33 + (c >> 1)] = prev | (hb << 16);
            else       prev = hb;
        }
        Sarr[p] = __fadd_rn(__fadd_rn(__fadd_rn(r[0], r[1]), __fadd_rn(r[2], r[3])),
                            __fadd_rn(__fadd_rn(r[4], r[5]), __fadd_rn(r[6], r[7])));
        // window: bf16-dot bound (slope 3x margin) + E_max(6.4e-5) + ref-rounding
        Wp[p] = 5.0e-5f * asum + 2.5e-4f;
        __syncthreads();
#pragma unroll
        for (int j = 0; j < 32; ++j) {                // coalesced u32 writes
            int lg = j * 256 + tid;
            zh[blockIdx.x * 8192 + lg] = lw[(lg >> 5) * 33 + (lg & 31)];
        }
    } else {
        const int mb = blockIdx.x - N_PIX / 256;
        const int m  = mb * 256 + tid;
        const float* rp = emb + m * C_DIM;
        float r[8]; u32 prev = 0;
#pragma unroll
        for (int c = 0; c < C_DIM; ++c) {
            float v  = rp[c];
            float sq = __fmul_rn(v, v);
            if (c < 8) r[c] = sq; else r[c & 7] = __fadd_rn(r[c & 7], sq);
            u32 hb = bf16rn(v);
            if (c & 1) lw[tid * 33 + (c >> 1)] = prev | (hb << 16);
            else       prev = hb;
        }
        Etab[m] = __fadd_rn(__fadd_rn(__fadd_rn(r[0], r[1]), __fadd_rn(r[2], r[3])),
                            __fadd_rn(__fadd_rn(r[4], r[5]), __fadd_rn(r[6], r[7])));
        __syncthreads();
#pragma unroll
        for (int j = 0; j < 32; ++j) {
            int lg = j * 256 + tid;
            eh[mb * 8192 + lg] = lw[(lg >> 5) * 33 + (lg & 31)];
        }
    }
}

// Coarse GEMM. Score = acc = zh.eh (bf16 MFMA); min dist <=> max acc
// (||e||^2 absorbed into Wp). Round-9/10 postmortem: VGPR_Count=52 proved
// the compiler rematerializes the A-fragment loads INSIDE the K-loop
// (8 extra global loads/iter, ~24 TB/s of hidden L2 traffic). Fix: pin af
// with an empty asm volatile — the value becomes asm-produced, remat is
// impossible, the 32 VGPRs must stay live. B: depth-2 named ping-pong
// (round-8 scratch lesson). Pass-0 epilogue pairs two cg's accs through
// fmax(fmax) -> v_max3_f32 (halves epilogue VALU).
// PASS 0: per-pixel max(acc) -> shfl -> LDS -> plain store cmin8[slice][pix].
// PASS 1: thr = decf(min8) + Wp; collect acc >= -thr/2 via LDS staging,
//         one global ticket per block (round-4 lesson).
template <int PASS>
__global__ __launch_bounds__(256)
void k_gemm(const bf16x8* __restrict__ zh8,
            const bf16x8* __restrict__ eh8,
            const float* __restrict__ Wp,
            u32* __restrict__ cmin8,
            u32* __restrict__ count,
            u32* __restrict__ list) {
    __shared__ u32  cm_l[M_BLK];         // pass-0 block-local min (encoded)
    __shared__ float thr_l[M_BLK];       // pass-1 raw thresholds
    __shared__ u32 loc_list[LOCBUF];     // 4 KB pass-1 candidate staging
    __shared__ u32 loc_cnt, glob_base;

    const int tid  = threadIdx.x;
    const int lane = tid & 63, w = tid >> 6;
    const int rg_id = w & 1;             // row-group: 64 rows each
    const int cg_id = w >> 1;            // code-group: 512 codes each
    const int q = lane >> 4, c15 = lane & 15;
    const int pixbase   = blockIdx.x * M_BLK;
    const int slicebase = blockIdx.y * N_SLICE;
    const int code0     = slicebase + cg_id * 512;

    // B prefetch (named vars only), issued first.
    const bf16x8* bpl = eh8 + (size_t)(code0 + c15) * 8 + q;
    bf16x8 n0a = bpl[0],   n1a = bpl[4];      // cg+0
    bf16x8 n0b = bpl[128], n1b = bpl[132];    // cg+1

    // A fragments straight from global (L2-hot, 8 x 16B per thread).
    const bf16x8* apl = zh8 + (size_t)(pixbase + rg_id * 64 + c15) * 8 + q;
    bf16x8 af[4][2];
#pragma unroll
    for (int rt = 0; rt < 4; ++rt) {
        af[rt][0] = apl[rt * 128];
        af[rt][1] = apl[rt * 128 + 4];
    }
    // PIN: value now produced by asm -> cannot be rematerialized; 32 VGPRs
    // stay live for the whole K-loop (this is the round-11 experiment).
#pragma unroll
    for (int rt = 0; rt < 4; ++rt)
        asm volatile("" : "+v"(af[rt][0]), "+v"(af[rt][1]));

    if (PASS == 0 && tid < M_BLK) cm_l[tid] = 0xFFFFFFFFu;
    if (PASS == 1) {
        if (tid < M_BLK) {
            u32 mn = 0xFFFFFFFFu;
#pragma unroll
            for (int s = 0; s < N_SLICES; ++s)
                mn = min(mn, cmin8[s * N_PIX + pixbase + tid]);  // encoded: u32 min ok
            thr_l[tid] = decf(mn) + Wp[pixbase + tid];
        }
        if (tid == 0) loc_cnt = 0u;
        __syncthreads();
    }

    float vmax[16];
    float nthr[16];
#pragma unroll
    for (int i = 0; i < 16; ++i) vmax[i] = -3.402823466e38f;
    if (PASS == 1) {
#pragma unroll
        for (int rt = 0; rt < 4; ++rt)
#pragma unroll
            for (int rg = 0; rg < 4; ++rg)   // acc >= -thr/2  <=>  -2acc <= thr
                nthr[rt * 4 + rg] = -0.5f * thr_l[rg_id * 64 + rt * 16 + q * 4 + rg];
    }

    // 512 codes, barrier-free, depth-2 ping-pong, two cg per body.
#pragma unroll 2
    for (int cg = 0; cg < 32; cg += 2) {
        bf16x8 c0 = n0a, c1 = n1a;
        if (cg + 2 < 32) { n0a = bpl[(cg + 2) * 128]; n1a = bpl[(cg + 2) * 128 + 4]; }
        bf16x8 d0 = n0b, d1 = n1b;
        if (cg + 3 < 32) { n0b = bpl[(cg + 3) * 128]; n1b = bpl[(cg + 3) * 128 + 4]; }
#pragma unroll
        for (int rt = 0; rt < 4; ++rt) {
            f32x4 acc0 = {0.f, 0.f, 0.f, 0.f};
            acc0 = __builtin_amdgcn_mfma_f32_16x16x32_bf16(af[rt][0], c0, acc0, 0, 0, 0);
            acc0 = __builtin_amdgcn_mfma_f32_16x16x32_bf16(af[rt][1], c1, acc0, 0, 0, 0);
            f32x4 acc1 = {0.f, 0.f, 0.f, 0.f};
            acc1 = __builtin_amdgcn_mfma_f32_16x16x32_bf16(af[rt][0], d0, acc1, 0, 0, 0);
            acc1 = __builtin_amdgcn_mfma_f32_16x16x32_bf16(af[rt][1], d1, acc1, 0, 0, 0);
#pragma unroll
            for (int rg = 0; rg < 4; ++rg) {
                if (PASS == 0) {
                    // fmax(fmax) -> v_max3_f32: 1 VALU op per 2 scores
                    vmax[rt * 4 + rg] = fmaxf(vmax[rt * 4 + rg],
                                              fmaxf(acc0[rg], acc1[rg]));
                } else {
                    if (acc0[rg] >= nthr[rt * 4 + rg]) {
                        int pixel = pixbase + rg_id * 64 + rt * 16 + q * 4 + rg;
                        int code  = code0 + cg * 16 + c15;
                        u32 entry = ((u32)pixel << 13) | (u32)code;
                        u32 pos = atomicAdd(&loc_cnt, 1u);
                        if (pos < LOCBUF) loc_list[pos] = entry;
                        else { u32 g = atomicAdd(count, 1u);
                               if (g < CAP) list[g] = entry; }
                    }
                    if (acc1[rg] >= nthr[rt * 4 + rg]) {
                        int pixel = pixbase + rg_id * 64 + rt * 16 + q * 4 + rg;
                        int code  = code0 + (cg + 1) * 16 + c15;
                        u32 entry = ((u32)pixel << 13) | (u32)code;
                        u32 pos = atomicAdd(&loc_cnt, 1u);
                        if (pos < LOCBUF) loc_list[pos] = entry;
                        else { u32 g = atomicAdd(count, 1u);
                               if (g < CAP) list[g] = entry; }
                    }
                }
            }
        }
    }

    if (PASS == 0) {
        // Reduce the 16 code-columns per row, LDS-combine, plain store.
#pragma unroll
        for (int i = 0; i < 16; ++i) {
            float v = vmax[i];
            v = fmaxf(v, __shfl_xor(v, 1));
            v = fmaxf(v, __shfl_xor(v, 2));
            v = fmaxf(v, __shfl_xor(v, 4));
            v = fmaxf(v, __shfl_xor(v, 8));
            if (c15 == 0) {
                int row = rg_id * 64 + (i >> 2) * 16 + q * 4 + (i & 3);
                atomicMin(&cm_l[row], encf(-2.0f * v));   // LDS atomic, cheap
            }
        }
        __syncthreads();
        if (tid < M_BLK)
            cmin8[blockIdx.y * N_PIX + pixbase + tid] = cm_l[tid];
    } else {
        // Block-level flush: one global ticket, coalesced list writes.
        __syncthreads();
        u32 n_loc = loc_cnt; if (n_loc > LOCBUF) n_loc = LOCBUF;
        if (tid == 0) glob_base = atomicAdd(count, n_loc);
        __syncthreads();
        u32 base = glob_base;
        for (u32 i = tid; i < n_loc; i += 256u) {
            u32 g = base + i;
            if (g < CAP) list[g] = loc_list[i];
        }
    }
}

// Exact refine: bit-identical reference distance chain per candidate pair.
__global__ __launch_bounds__(256) void k_refine(const float* __restrict__ z,
                                                const float* __restrict__ emb,
                                                const float* __restrict__ Sarr,
                                                const float* __restrict__ Etab,
                                                const u32* __restrict__ count,
                                                const u32* __restrict__ list,
                                                u64* __restrict__ best) {
    u32 cnt = *count; if (cnt > CAP) cnt = CAP;
    for (u32 i = blockIdx.x * 256 + threadIdx.x; i < cnt; i += 256u * 256u) {
        u32 e = list[i];
        int pixel = (int)(e >> 13), code = (int)(e & 8191u);
        const float* zp = z + (pixel >> 12) * BHW + (pixel & 4095);
        const float* ep = emb + code * C_DIM;
        float dot = 0.0f;
#pragma unroll
        for (int c = 0; c < C_DIM; ++c)
            dot = __builtin_fmaf(zp[c * HW], ep[c], dot);
        float dist = __fsub_rn(__fadd_rn(Sarr[pixel], Etab[code]),
                               __fmul_rn(2.0f, dot));
        u64 key = ((u64)__float_as_uint(dist) << 32) | (u32)code;  // dist > 0
        atomicMin(&best[pixel], key);
    }
}

// Gather z_q, write idx + z_q_st (NCHW); f64 loss via global atomicAdd,
// last-finishing block (done-counter) writes out[0].
__global__ __launch_bounds__(256) void k_final(const float* __restrict__ z,
                                               const float* __restrict__ emb,
                                               const u64* __restrict__ best,
                                               float* __restrict__ out,
                                               double* __restrict__ loss_acc,
                                               u32* __restrict__ done) {
    const int n  = blockIdx.x * 256 + threadIdx.x;
    const int b  = n >> 12;
    const int hw = n & 4095;
    const u32 m  = (u32)(best[n] & 0xFFFFFFFFull);
    out[OUT_IDX_OFF + n] = (float)m;

    const float* zp = z + b * BHW + hw;
    const float* e  = emb + m * C_DIM;
    double lacc = 0.0;
#pragma unroll
    for (int c = 0; c < 64; ++c) {
        float zz   = zp[c * HW];
        float ec   = e[c];
        float diff = __fsub_rn(ec, zz);
        float outv = __fadd_rn(zz, diff);
        out[OUT_ZQ_OFF + b * BHW + c * HW + hw] = outv;
        lacc += (double)__fmul_rn(diff, diff);
    }
    __shared__ double sh[256];
    sh[threadIdx.x] = lacc;
    __syncthreads();
#pragma unroll
    for (int s = 128; s > 0; s >>= 1) {
        if (threadIdx.x < s) sh[threadIdx.x] += sh[threadIdx.x + s];
        __syncthreads();
    }
    if (threadIdx.x == 0) {
        atomicAdd(loss_acc, sh[0]);                 // device-scope f64 add
        __threadfence();
        u32 d = atomicAdd(done, 1u);
        if (d == (N_PIX / 256) - 1) {               // last block
            double s = atomicAdd(loss_acc, 0.0);    // atomic read of full sum
            float m1 = (float)(s / (double)ZQ_N);
            out[0] = __fadd_rn(m1, __fmul_rn(0.25f, m1));
        }
    }
}

extern "C" void kernel_launch(void* const* d_in, const int* in_sizes, int n_in,
                              void* d_out, int out_size, void* d_ws, size_t ws_size,
                              hipStream_t stream) {
    const float* z   = (const float*)d_in[0];
    const float* emb = (const float*)d_in[1];
    float* out = (float*)d_out;

    char* ws = (char*)d_ws;
    u64*    best  = (u64*)ws;
    float*  Etab  = (float*)(ws + WS_E_OFF);
    u32*    count = (u32*)(ws + WS_C_OFF);
    u32*    done  = (u32*)(ws + WS_D_OFF);
    double* lacc  = (double*)(ws + WS_A_OFF);

    float* SCR = out + 4;                       // 16B-aligned scratch in zq region
    u32*   zh    = (u32*)(SCR + OFF_ZH);
    u32*   eh    = (u32*)(SCR + OFF_EH);
    float* Sarr  = SCR + OFF_S;
    float* Wp    = SCR + OFF_W;
    u32*   cmin8 = (u32*)(SCR + OFF_CMIN8);
    u32*   list  = (u32*)(SCR + OFF_LIST);

    k_prep<<<dim3(N_PIX / 256 + NE / 256), dim3(256), 0, stream>>>(
        z, emb, zh, eh, Sarr, Wp, Etab, best, count, done, lacc);
    k_gemm<0><<<dim3(N_PIX / M_BLK, N_SLICES), dim3(256), 0, stream>>>(
        (const bf16x8*)zh, (const bf16x8*)eh, Wp, cmin8, count, list);
    k_gemm<1><<<dim3(N_PIX / M_BLK, N_SLICES), dim3(256), 0, stream>>>(
        (const bf16x8*)zh, (const bf16x8*)eh, Wp, cmin8, count, list);
    k_refine<<<dim3(256), dim3(256), 0, stream>>>(z, emb, Sarr, Etab, count, list, best);
    k_final <<<dim3(N_PIX / 256), dim3(256), 0, stream>>>(z, emb, best, out, lacc, done);
}

// Round 12
// 199.525 us; speedup vs baseline: 1.5789x; 1.2410x over previous
//
#include <hip/hip_runtime.h>

typedef unsigned int u32;
typedef unsigned long long u64;
typedef __bf16 bf16x8 __attribute__((ext_vector_type(8)));
typedef float f32x4 __attribute__((ext_vector_type(4)));

// Problem constants
#define N_PIX   32768        // 8*64*64 pixels
#define C_DIM   64
#define NE      8192
#define HW      4096         // 64*64
#define BHW     262144       // elements per batch in z (64*4096)
#define ZQ_N    2097152      // 8*64*64*64

// Output layout (flat f32): [0]=loss, [1..2097152]=z_q_out(NCHW), [2097153..]=idx
#define OUT_ZQ_OFF  1
#define OUT_IDX_OFF (1 + ZQ_N)

// Scratch inside d_out's zq region (overwritten by k_final at the end).
// SCR = out + 4 floats (16B aligned). Offsets in 4-byte slots relative to SCR:
// zh/eh are stored FRAGMENT-MAJOR (round-12): for rowgroup g=row>>4, chunk
// j=dword>>2 (16B of feats j*8..j*8+8), lane c15=row&15:
//   off32 = g*512 + j*64 + c15*4 + (dword&3)
// => gemm loads are base + lane*16B: perfectly coalesced 1KB segments.
#define OFF_ZH    0         // u32[1048576]  : zh bf16 pairs, fragment-major
#define OFF_EH    1048576   // u32[262144]   : eh bf16 pairs, fragment-major
#define OFF_S     1310720   // f32[32768]    : ||z||^2 exact pairwise
#define OFF_W     1343488   // f32[32768]    : refine window per pixel
#define OFF_CMIN8 1376256   // u32[8*32768]  : per-slice order-encoded coarse min
#define OFF_LIST  1638400   // u32[CAP]      : candidate (pixel<<13|code)
#define CAP       458744

// Workspace (ws) layout:
#define WS_E_OFF  262144   // f32 Etab[8192] after u64 best[32768]
#define WS_C_OFF  294912   // u32 count
#define WS_D_OFF  294916   // u32 done (k_final last-block counter)
#define WS_A_OFF  294920   // f64 loss_acc

// GEMM tiling (round-9 best shape): block = 256 thr = 4 waves =
// 2 row-groups x 2 code-groups. Wave = 64 pixel-rows x 512 codes from L2.
#define M_BLK    128
#define N_SLICE  1024
#define N_SLICES 8         // NE / N_SLICE
#define LOCBUF   1024      // per-block candidate staging (expected ~30/block)

__device__ __forceinline__ u32 encf(float v) {
    u32 u = __float_as_uint(v);
    return (u & 0x80000000u) ? ~u : (u | 0x80000000u);
}
__device__ __forceinline__ float decf(u32 k) {
    return (k & 0x80000000u) ? __uint_as_float(k ^ 0x80000000u)
                             : __uint_as_float(~k);
}
__device__ __forceinline__ u32 bf16rn(float v) {      // RNE f32->bf16 bits
    u32 u = __float_as_uint(v);
    return (u + 0x7FFFu + ((u >> 16) & 1u)) >> 16;
}
// fragment-major offset (in u32 units) for row r, row-dword u (0..31)
__device__ __forceinline__ int frag_off(int r, int u) {
    return (r >> 4) * 512 + (u >> 2) * 64 + (r & 15) * 4 + (u & 3);
}

// Fused prep: blocks [0,128) process z (pixels), blocks [128,160) process emb.
// z-part also does all one-time inits (best, count/done/loss_acc).
__global__ __launch_bounds__(256) void k_prep(const float* __restrict__ z,
                                              const float* __restrict__ emb,
                                              u32* __restrict__ zh,
                                              u32* __restrict__ eh,
                                              float* __restrict__ Sarr,
                                              float* __restrict__ Wp,
                                              float* __restrict__ Etab,
                                              u64* __restrict__ best,
                                              u32* __restrict__ count,
                                              u32* __restrict__ done,
                                              double* __restrict__ loss_acc) {
    __shared__ u32 lw[256 * 33];
    const int tid = threadIdx.x;
    if (blockIdx.x < N_PIX / 256) {
        const int p = blockIdx.x * 256 + tid;
        best[p] = ~0ull;
        if (blockIdx.x == 0 && tid == 0) { *count = 0u; *done = 0u; *loss_acc = 0.0; }
        const float* zp = z + (p >> 12) * BHW + (p & 4095);
        float r[8]; float asum = 0.0f; u32 prev = 0;
#pragma unroll
        for (int c = 0; c < C_DIM; ++c) {
            float v  = zp[c * HW];                    // coalesced
            float sq = __fmul_rn(v, v);
            if (c < 8) r[c] = sq; else r[c & 7] = __fadd_rn(r[c & 7], sq);
            asum += fabsf(v);
            u32 hb = bf16rn(v);
            if (c & 1) lw[tid * 33 + (c >> 1)] = prev | (hb << 16);
            else       prev = hb;
        }
        Sarr[p] = __fadd_rn(__fadd_rn(__fadd_rn(r[0], r[1]), __fadd_rn(r[2], r[3])),
                            __fadd_rn(__fadd_rn(r[4], r[5]), __fadd_rn(r[6], r[7])));
        // window: bf16-dot bound (slope 3x margin) + E_max(6.4e-5) + ref-rounding
        Wp[p] = 5.0e-5f * asum + 2.5e-4f;
        __syncthreads();
#pragma unroll
        for (int j = 0; j < 32; ++j) {                // fragment-major writes
            int lg = j * 256 + tid;
            int pl = lg >> 5, u = lg & 31;
            zh[frag_off(blockIdx.x * 256 + pl, u)] = lw[pl * 33 + u];
        }
    } else {
        const int mb = blockIdx.x - N_PIX / 256;
        const int m  = mb * 256 + tid;
        const float* rp = emb + m * C_DIM;
        float r[8]; u32 prev = 0;
#pragma unroll
        for (int c = 0; c < C_DIM; ++c) {
            float v  = rp[c];
            float sq = __fmul_rn(v, v);
            if (c < 8) r[c] = sq; else r[c & 7] = __fadd_rn(r[c & 7], sq);
            u32 hb = bf16rn(v);
            if (c & 1) lw[tid * 33 + (c >> 1)] = prev | (hb << 16);
            else       prev = hb;
        }
        Etab[m] = __fadd_rn(__fadd_rn(__fadd_rn(r[0], r[1]), __fadd_rn(r[2], r[3])),
                            __fadd_rn(__fadd_rn(r[4], r[5]), __fadd_rn(r[6], r[7])));
        __syncthreads();
#pragma unroll
        for (int j = 0; j < 32; ++j) {                // fragment-major writes
            int lg = j * 256 + tid;
            int ml = lg >> 5, u = lg & 31;
            eh[frag_off(mb * 256 + ml, u)] = lw[ml * 33 + u];
        }
    }
}

// Coarse GEMM. Score = acc = zh.eh (bf16 MFMA); min dist <=> max acc
// (||e||^2 absorbed into Wp). Round-11 postmortem: the 128-B-strided 16B
// lane-gathers were the wall (4x line inflation, 16 segments/instr => TA/L1
// transaction bound ~55us/pass). Round 12: zh/eh stored fragment-major, so
// every A/B load is base + lane*16 — one dense 1KB segment per instruction.
// B: depth-2 named ping-pong (round-8 scratch lesson). af pinned via asm
// (round-11; keeps the one-time loads from being rematerialized).
// PASS 0: per-pixel max(acc) -> shfl -> LDS -> plain store cmin8[slice][pix].
// PASS 1: thr = decf(min8) + Wp; collect acc >= -thr/2 via LDS staging,
//         one global ticket per block (round-4 lesson).
template <int PASS>
__global__ __launch_bounds__(256)
void k_gemm(const bf16x8* __restrict__ zh8,
            const bf16x8* __restrict__ eh8,
            const float* __restrict__ Wp,
            u32* __restrict__ cmin8,
            u32* __restrict__ count,
            u32* __restrict__ list) {
    __shared__ u32  cm_l[M_BLK];         // pass-0 block-local min (encoded)
    __shared__ float thr_l[M_BLK];       // pass-1 raw thresholds
    __shared__ u32 loc_list[LOCBUF];     // 4 KB pass-1 candidate staging
    __shared__ u32 loc_cnt, glob_base;

    const int tid  = threadIdx.x;
    const int lane = tid & 63, w = tid >> 6;
    const int rg_id = w & 1;             // row-group: 64 rows each
    const int cg_id = w >> 1;            // code-group: 512 codes each
    const int q = lane >> 4, c15 = lane & 15;
    const int pixbase   = blockIdx.x * M_BLK;
    const int slicebase = blockIdx.y * N_SLICE;
    const int code0     = slicebase + cg_id * 512;

    // B prefetch (named vars only): fragment-major => base + lane*16B.
    // Per 16-code group cg: b0 at cg*128+lane, b1 at cg*128+64+lane (bf16x8 units).
    const bf16x8* bpl = eh8 + (size_t)(code0 >> 4) * 128 + lane;
    bf16x8 n0a = bpl[0],   n1a = bpl[64];     // cg+0
    bf16x8 n0b = bpl[128], n1b = bpl[192];    // cg+1

    // A fragments, fragment-major, fully coalesced; one-time load.
    const int rowgrp0 = (pixbase >> 4) + rg_id * 4;
    const bf16x8* apl = zh8 + (size_t)rowgrp0 * 128 + lane;
    bf16x8 af[4][2];
#pragma unroll
    for (int rt = 0; rt < 4; ++rt) {
        af[rt][0] = apl[rt * 128];
        af[rt][1] = apl[rt * 128 + 64];
    }
    // PIN: asm-produced values cannot be rematerialized (round-11 lesson).
#pragma unroll
    for (int rt = 0; rt < 4; ++rt)
        asm volatile("" : "+v"(af[rt][0]), "+v"(af[rt][1]));

    if (PASS == 0 && tid < M_BLK) cm_l[tid] = 0xFFFFFFFFu;
    if (PASS == 1) {
        if (tid < M_BLK) {
            u32 mn = 0xFFFFFFFFu;
#pragma unroll
            for (int s = 0; s < N_SLICES; ++s)
                mn = min(mn, cmin8[s * N_PIX + pixbase + tid]);  // encoded: u32 min ok
            thr_l[tid] = decf(mn) + Wp[pixbase + tid];
        }
        if (tid == 0) loc_cnt = 0u;
        __syncthreads();
    }

    float vmax[16];
    float nthr[16];
#pragma unroll
    for (int i = 0; i < 16; ++i) vmax[i] = -3.402823466e38f;
    if (PASS == 1) {
#pragma unroll
        for (int rt = 0; rt < 4; ++rt)
#pragma unroll
            for (int rg = 0; rg < 4; ++rg)   // acc >= -thr/2  <=>  -2acc <= thr
                nthr[rt * 4 + rg] = -0.5f * thr_l[rg_id * 64 + rt * 16 + q * 4 + rg];
    }

    // 512 codes, barrier-free, depth-2 ping-pong, two cg per body.
#pragma unroll 2
    for (int cg = 0; cg < 32; cg += 2) {
        bf16x8 c0 = n0a, c1 = n1a;
        if (cg + 2 < 32) { n0a = bpl[(cg + 2) * 128]; n1a = bpl[(cg + 2) * 128 + 64]; }
        bf16x8 d0 = n0b, d1 = n1b;
        if (cg + 3 < 32) { n0b = bpl[(cg + 3) * 128]; n1b = bpl[(cg + 3) * 128 + 64]; }
#pragma unroll
        for (int rt = 0; rt < 4; ++rt) {
            f32x4 acc0 = {0.f, 0.f, 0.f, 0.f};
            acc0 = __builtin_amdgcn_mfma_f32_16x16x32_bf16(af[rt][0], c0, acc0, 0, 0, 0);
            acc0 = __builtin_amdgcn_mfma_f32_16x16x32_bf16(af[rt][1], c1, acc0, 0, 0, 0);
            f32x4 acc1 = {0.f, 0.f, 0.f, 0.f};
            acc1 = __builtin_amdgcn_mfma_f32_16x16x32_bf16(af[rt][0], d0, acc1, 0, 0, 0);
            acc1 = __builtin_amdgcn_mfma_f32_16x16x32_bf16(af[rt][1], d1, acc1, 0, 0, 0);
#pragma unroll
            for (int rg = 0; rg < 4; ++rg) {
                if (PASS == 0) {
                    // fmax(fmax) -> v_max3_f32: 1 VALU op per 2 scores
                    vmax[rt * 4 + rg] = fmaxf(vmax[rt * 4 + rg],
                                              fmaxf(acc0[rg], acc1[rg]));
                } else {
                    if (acc0[rg] >= nthr[rt * 4 + rg]) {
                        int pixel = pixbase + rg_id * 64 + rt * 16 + q * 4 + rg;
                        int code  = code0 + cg * 16 + c15;
                        u32 entry = ((u32)pixel << 13) | (u32)code;
                        u32 pos = atomicAdd(&loc_cnt, 1u);
                        if (pos < LOCBUF) loc_list[pos] = entry;
                        else { u32 g = atomicAdd(count, 1u);
                               if (g < CAP) list[g] = entry; }
                    }
                    if (acc1[rg] >= nthr[rt * 4 + rg]) {
                        int pixel = pixbase + rg_id * 64 + rt * 16 + q * 4 + rg;
                        int code  = code0 + (cg + 1) * 16 + c15;
                        u32 entry = ((u32)pixel << 13) | (u32)code;
                        u32 pos = atomicAdd(&loc_cnt, 1u);
                        if (pos < LOCBUF) loc_list[pos] = entry;
                        else { u32 g = atomicAdd(count, 1u);
                               if (g < CAP) list[g] = entry; }
                    }
                }
            }
        }
    }

    if (PASS == 0) {
        // Reduce the 16 code-columns per row, LDS-combine, plain store.
#pragma unroll
        for (int i = 0; i < 16; ++i) {
            float v = vmax[i];
            v = fmaxf(v, __shfl_xor(v, 1));
            v = fmaxf(v, __shfl_xor(v, 2));
            v = fmaxf(v, __shfl_xor(v, 4));
            v = fmaxf(v, __shfl_xor(v, 8));
            if (c15 == 0) {
                int row = rg_id * 64 + (i >> 2) * 16 + q * 4 + (i & 3);
                atomicMin(&cm_l[row], encf(-2.0f * v));   // LDS atomic, cheap
            }
        }
        __syncthreads();
        if (tid < M_BLK)
            cmin8[blockIdx.y * N_PIX + pixbase + tid] = cm_l[tid];
    } else {
        // Block-level flush: one global ticket, coalesced list writes.
        __syncthreads();
        u32 n_loc = loc_cnt; if (n_loc > LOCBUF) n_loc = LOCBUF;
        if (tid == 0) glob_base = atomicAdd(count, n_loc);
        __syncthreads();
        u32 base = glob_base;
        for (u32 i = tid; i < n_loc; i += 256u) {
            u32 g = base + i;
            if (g < CAP) list[g] = loc_list[i];
        }
    }
}

// Exact refine: bit-identical reference distance chain per candidate pair.
__global__ __launch_bounds__(256) void k_refine(const float* __restrict__ z,
                                                const float* __restrict__ emb,
                                                const float* __restrict__ Sarr,
                                                const float* __restrict__ Etab,
                                                const u32* __restrict__ count,
                                                const u32* __restrict__ list,
                                                u64* __restrict__ best) {
    u32 cnt = *count; if (cnt > CAP) cnt = CAP;
    for (u32 i = blockIdx.x * 256 + threadIdx.x; i < cnt; i += 256u * 256u) {
        u32 e = list[i];
        int pixel = (int)(e >> 13), code = (int)(e & 8191u);
        const float* zp = z + (pixel >> 12) * BHW + (pixel & 4095);
        const float* ep = emb + code * C_DIM;
        float dot = 0.0f;
#pragma unroll
        for (int c = 0; c < C_DIM; ++c)
            dot = __builtin_fmaf(zp[c * HW], ep[c], dot);
        float dist = __fsub_rn(__fadd_rn(Sarr[pixel], Etab[code]),
                               __fmul_rn(2.0f, dot));
        u64 key = ((u64)__float_as_uint(dist) << 32) | (u32)code;  // dist > 0
        atomicMin(&best[pixel], key);
    }
}

// Gather z_q, write idx + z_q_st (NCHW); f64 loss via global atomicAdd,
// last-finishing block (done-counter) writes out[0].
__global__ __launch_bounds__(256) void k_final(const float* __restrict__ z,
                                               const float* __restrict__ emb,
                                               const u64* __restrict__ best,
                                               float* __restrict__ out,
                                               double* __restrict__ loss_acc,
                                               u32* __restrict__ done) {
    const int n  = blockIdx.x * 256 + threadIdx.x;
    const int b  = n >> 12;
    const int hw = n & 4095;
    const u32 m  = (u32)(best[n] & 0xFFFFFFFFull);
    out[OUT_IDX_OFF + n] = (float)m;

    const float* zp = z + b * BHW + hw;
    const float* e  = emb + m * C_DIM;
    double lacc = 0.0;
#pragma unroll
    for (int c = 0; c < 64; ++c) {
        float zz   = zp[c * HW];
        float ec   = e[c];
        float diff = __fsub_rn(ec, zz);
        float outv = __fadd_rn(zz, diff);
        out[OUT_ZQ_OFF + b * BHW + c * HW + hw] = outv;
        lacc += (double)__fmul_rn(diff, diff);
    }
    __shared__ double sh[256];
    sh[threadIdx.x] = lacc;
    __syncthreads();
#pragma unroll
    for (int s = 128; s > 0; s >>= 1) {
        if (threadIdx.x < s) sh[threadIdx.x] += sh[threadIdx.x + s];
        __syncthreads();
    }
    if (threadIdx.x == 0) {
        atomicAdd(loss_acc, sh[0]);                 // device-scope f64 add
        __threadfence();
        u32 d = atomicAdd(done, 1u);
        if (d == (N_PIX / 256) - 1) {               // last block
            double s = atomicAdd(loss_acc, 0.0);    // atomic read of full sum
            float m1 = (float)(s / (double)ZQ_N);
            out[0] = __fadd_rn(m1, __fmul_rn(0.25f, m1));
        }
    }
}

extern "C" void kernel_launch(void* const* d_in, const int* in_sizes, int n_in,
                              void* d_out, int out_size, void* d_ws, size_t ws_size,
                              hipStream_t stream) {
    const float* z   = (const float*)d_in[0];
    const float* emb = (const float*)d_in[1];
    float* out = (float*)d_out;

    char* ws = (char*)d_ws;
    u64*    best  = (u64*)ws;
    float*  Etab  = (float*)(ws + WS_E_OFF);
    u32*    count = (u32*)(ws + WS_C_OFF);
    u32*    done  = (u32*)(ws + WS_D_OFF);
    double* lacc  = (double*)(ws + WS_A_OFF);

    float* SCR = out + 4;                       // 16B-aligned scratch in zq region
    u32*   zh    = (u32*)(SCR + OFF_ZH);
    u32*   eh    = (u32*)(SCR + OFF_EH);
    float* Sarr  = SCR + OFF_S;
    float* Wp    = SCR + OFF_W;
    u32*   cmin8 = (u32*)(SCR + OFF_CMIN8);
    u32*   list  = (u32*)(SCR + OFF_LIST);

    k_prep<<<dim3(N_PIX / 256 + NE / 256), dim3(256), 0, stream>>>(
        z, emb, zh, eh, Sarr, Wp, Etab, best, count, done, lacc);
    k_gemm<0><<<dim3(N_PIX / M_BLK, N_SLICES), dim3(256), 0, stream>>>(
        (const bf16x8*)zh, (const bf16x8*)eh, Wp, cmin8, count, list);
    k_gemm<1><<<dim3(N_PIX / M_BLK, N_SLICES), dim3(256), 0, stream>>>(
        (const bf16x8*)zh, (const bf16x8*)eh, Wp, cmin8, count, list);
    k_refine<<<dim3(256), dim3(256), 0, stream>>>(z, emb, Sarr, Etab, count, list, best);
    k_final <<<dim3(N_PIX / 256), dim3(256), 0, stream>>>(z, emb, best, out, lacc, done);
}

// Round 14
// 198.131 us; speedup vs baseline: 1.5901x; 1.0070x over previous
//
#include <hip/hip_runtime.h>

typedef unsigned int u32;
typedef unsigned long long u64;
typedef __bf16 bf16x8 __attribute__((ext_vector_type(8)));
typedef float f32x4 __attribute__((ext_vector_type(4)));

// Problem constants
#define N_PIX   32768        // 8*64*64 pixels
#define C_DIM   64
#define NE      8192
#define HW      4096         // 64*64
#define BHW     262144       // elements per batch in z (64*4096)
#define ZQ_N    2097152      // 8*64*64*64

// Output layout (flat f32): [0]=loss, [1..2097152]=z_q_out(NCHW), [2097153..]=idx
#define OUT_ZQ_OFF  1
#define OUT_IDX_OFF (1 + ZQ_N)

// Scratch inside d_out's zq region (overwritten by k_final at the end).
// SCR = out + 4 floats (16B aligned). Offsets in 4-byte slots relative to SCR:
// zh/eh are FRAGMENT-MAJOR (round-12 win): rowgroup g=row>>4, chunk j=u>>2,
// lane c15=row&15: off32 = g*512 + j*64 + c15*4 + (u&3)
// => gemm loads are base + lane*16B: dense 1KB segments per instruction.
#define OFF_ZH    0         // u32[1048576]  : zh bf16 pairs, fragment-major
#define OFF_EH    1048576   // u32[262144]   : eh bf16 pairs, fragment-major
#define OFF_S     1310720   // f32[32768]    : ||z||^2 exact pairwise
#define OFF_W     1343488   // f32[32768]    : refine window per pixel
#define OFF_CMIN8 1376256   // u32[8*32768]  : per-slice order-encoded coarse min
#define OFF_LIST  1638400   // u32[CAP]      : candidate (pixel<<13|code)
#define CAP       458744

// Workspace (ws) layout:
#define WS_E_OFF  262144   // f32 Etab[8192] after u64 best[32768]
#define WS_C_OFF  294912   // u32 count
#define WS_D_OFF  294916   // u32 done (k_final last-block counter)
#define WS_A_OFF  294920   // f64 loss_acc

// GEMM tiling (round-9/12 verified shape): block = 256 thr = 4 waves =
// 2 row-groups x 2 code-groups. Wave = 64 pixel-rows x 512 codes from L2.
#define M_BLK    128
#define N_SLICE  1024
#define N_SLICES 8         // NE / N_SLICE
#define LOCBUF   1024      // per-block candidate staging (expected ~30/block)

__device__ __forceinline__ u32 encf(float v) {
    u32 u = __float_as_uint(v);
    return (u & 0x80000000u) ? ~u : (u | 0x80000000u);
}
__device__ __forceinline__ float decf(u32 k) {
    return (k & 0x80000000u) ? __uint_as_float(k ^ 0x80000000u)
                             : __uint_as_float(~k);
}
__device__ __forceinline__ u32 bf16rn(float v) {      // RNE f32->bf16 bits
    u32 u = __float_as_uint(v);
    return (u + 0x7FFFu + ((u >> 16) & 1u)) >> 16;
}
// fragment-major offset (in u32 units) for row r, row-dword u (0..31)
__device__ __forceinline__ int frag_off(int r, int u) {
    return (r >> 4) * 512 + (u >> 2) * 64 + (r & 15) * 4 + (u & 3);
}

// Fused prep: blocks [0,128) process z (pixels), blocks [128,160) process emb.
// z-part also does all one-time inits (best, count/done/loss_acc).
__global__ __launch_bounds__(256) void k_prep(const float* __restrict__ z,
                                              const float* __restrict__ emb,
                                              u32* __restrict__ zh,
                                              u32* __restrict__ eh,
                                              float* __restrict__ Sarr,
                                              float* __restrict__ Wp,
                                              float* __restrict__ Etab,
                                              u64* __restrict__ best,
                                              u32* __restrict__ count,
                                              u32* __restrict__ done,
                                              double* __restrict__ loss_acc) {
    __shared__ u32 lw[256 * 33];
    const int tid = threadIdx.x;
    if (blockIdx.x < N_PIX / 256) {
        const int p = blockIdx.x * 256 + tid;
        best[p] = ~0ull;
        if (blockIdx.x == 0 && tid == 0) { *count = 0u; *done = 0u; *loss_acc = 0.0; }
        const float* zp = z + (p >> 12) * BHW + (p & 4095);
        float r[8]; float asum = 0.0f; u32 prev = 0;
#pragma unroll
        for (int c = 0; c < C_DIM; ++c) {
            float v  = zp[c * HW];                    // coalesced
            float sq = __fmul_rn(v, v);
            if (c < 8) r[c] = sq; else r[c & 7] = __fadd_rn(r[c & 7], sq);
            asum += fabsf(v);
            u32 hb = bf16rn(v);
            if (c & 1) lw[tid * 33 + (c >> 1)] = prev | (hb << 16);
            else       prev = hb;
        }
        Sarr[p] = __fadd_rn(__fadd_rn(__fadd_rn(r[0], r[1]), __fadd_rn(r[2], r[3])),
                            __fadd_rn(__fadd_rn(r[4], r[5]), __fadd_rn(r[6], r[7])));
        // window: bf16-dot bound (slope 3x margin) + E_max(6.4e-5) + ref-rounding
        Wp[p] = 5.0e-5f * asum + 2.5e-4f;
        __syncthreads();
#pragma unroll
        for (int j = 0; j < 32; ++j) {                // fragment-major writes
            int lg = j * 256 + tid;
            int pl = lg >> 5, u = lg & 31;
            zh[frag_off(blockIdx.x * 256 + pl, u)] = lw[pl * 33 + u];
        }
    } else {
        const int mb = blockIdx.x - N_PIX / 256;
        const int m  = mb * 256 + tid;
        const float* rp = emb + m * C_DIM;
        float r[8]; u32 prev = 0;
#pragma unroll
        for (int c = 0; c < C_DIM; ++c) {
            float v  = rp[c];
            float sq = __fmul_rn(v, v);
            if (c < 8) r[c] = sq; else r[c & 7] = __fadd_rn(r[c & 7], sq);
            u32 hb = bf16rn(v);
            if (c & 1) lw[tid * 33 + (c >> 1)] = prev | (hb << 16);
            else       prev = hb;
        }
        Etab[m] = __fadd_rn(__fadd_rn(__fadd_rn(r[0], r[1]), __fadd_rn(r[2], r[3])),
                            __fadd_rn(__fadd_rn(r[4], r[5]), __fadd_rn(r[6], r[7])));
        __syncthreads();
#pragma unroll
        for (int j = 0; j < 32; ++j) {                // fragment-major writes
            int lg = j * 256 + tid;
            int ml = lg >> 5, u = lg & 31;
            eh[frag_off(mb * 256 + ml, u)] = lw[ml * 33 + u];
        }
    }
}

// Coarse GEMM (round-12 verified). Score = acc = zh.eh (bf16 MFMA); min dist
// <=> max acc (||e||^2 absorbed into Wp). zh/eh fragment-major => every A/B
// load is base + lane*16, one dense 1KB segment per instruction (round-12
// fix for the TA/L1 transaction wall). B: depth-2 named ping-pong (round-8
// scratch lesson). af pinned via asm (round-11 anti-remat).
// PASS 0: per-pixel max(acc) -> shfl -> LDS -> plain store cmin8[slice][pix].
// PASS 1: thr = decf(min8) + Wp; collect acc >= -thr/2 via LDS staging,
//         one global ticket per block (round-4 lesson).
template <int PASS>
__global__ __launch_bounds__(256)
void k_gemm(const bf16x8* __restrict__ zh8,
            const bf16x8* __restrict__ eh8,
            const float* __restrict__ Wp,
            u32* __restrict__ cmin8,
            u32* __restrict__ count,
            u32* __restrict__ list) {
    __shared__ u32  cm_l[M_BLK];         // pass-0 block-local min (encoded)
    __shared__ float thr_l[M_BLK];       // pass-1 raw thresholds
    __shared__ u32 loc_list[LOCBUF];     // 4 KB pass-1 candidate staging
    __shared__ u32 loc_cnt, glob_base;

    const int tid  = threadIdx.x;
    const int lane = tid & 63, w = tid >> 6;
    const int rg_id = w & 1;             // row-group: 64 rows each
    const int cg_id = w >> 1;            // code-group: 512 codes each
    const int q = lane >> 4, c15 = lane & 15;
    const int pixbase   = blockIdx.x * M_BLK;
    const int slicebase = blockIdx.y * N_SLICE;
    const int code0     = slicebase + cg_id * 512;

    // B prefetch (named vars only): fragment-major => base + lane*16B.
    const bf16x8* bpl = eh8 + (size_t)(code0 >> 4) * 128 + lane;
    bf16x8 n0a = bpl[0],   n1a = bpl[64];     // cg+0
    bf16x8 n0b = bpl[128], n1b = bpl[192];    // cg+1

    // A fragments, fragment-major, fully coalesced; one-time load.
    const int rowgrp0 = (pixbase >> 4) + rg_id * 4;
    const bf16x8* apl = zh8 + (size_t)rowgrp0 * 128 + lane;
    bf16x8 af[4][2];
#pragma unroll
    for (int rt = 0; rt < 4; ++rt) {
        af[rt][0] = apl[rt * 128];
        af[rt][1] = apl[rt * 128 + 64];
    }
    // PIN: asm-produced values cannot be rematerialized (round-11 lesson).
#pragma unroll
    for (int rt = 0; rt < 4; ++rt)
        asm volatile("" : "+v"(af[rt][0]), "+v"(af[rt][1]));

    if (PASS == 0) {
        if (tid < M_BLK) cm_l[tid] = 0xFFFFFFFFu;
        __syncthreads();   // round-14 hardening: init visible before any
                           // wave's epilogue atomicMin (race was benign-by-
                           // analysis, now impossible-by-construction)
    }
    if (PASS == 1) {
        if (tid < M_BLK) {
            u32 mn = 0xFFFFFFFFu;
#pragma unroll
            for (int s = 0; s < N_SLICES; ++s)
                mn = min(mn, cmin8[s * N_PIX + pixbase + tid]);  // encoded: u32 min ok
            thr_l[tid] = decf(mn) + Wp[pixbase + tid];
        }
        if (tid == 0) loc_cnt = 0u;
        __syncthreads();
    }

    float vmax[16];
    float nthr[16];
#pragma unroll
    for (int i = 0; i < 16; ++i) vmax[i] = -3.402823466e38f;
    if (PASS == 1) {
#pragma unroll
        for (int rt = 0; rt < 4; ++rt)
#pragma unroll
            for (int rg = 0; rg < 4; ++rg)   // acc >= -thr/2  <=>  -2acc <= thr
                nthr[rt * 4 + rg] = -0.5f * thr_l[rg_id * 64 + rt * 16 + q * 4 + rg];
    }

    // 512 codes, barrier-free, depth-2 ping-pong, two cg per body.
#pragma unroll 2
    for (int cg = 0; cg < 32; cg += 2) {
        bf16x8 c0 = n0a, c1 = n1a;
        if (cg + 2 < 32) { n0a = bpl[(cg + 2) * 128]; n1a = bpl[(cg + 2) * 128 + 64]; }
        bf16x8 d0 = n0b, d1 = n1b;
        if (cg + 3 < 32) { n0b = bpl[(cg + 3) * 128]; n1b = bpl[(cg + 3) * 128 + 64]; }
#pragma unroll
        for (int rt = 0; rt < 4; ++rt) {
            f32x4 acc0 = {0.f, 0.f, 0.f, 0.f};
            acc0 = __builtin_amdgcn_mfma_f32_16x16x32_bf16(af[rt][0], c0, acc0, 0, 0, 0);
            acc0 = __builtin_amdgcn_mfma_f32_16x16x32_bf16(af[rt][1], c1, acc0, 0, 0, 0);
            f32x4 acc1 = {0.f, 0.f, 0.f, 0.f};
            acc1 = __builtin_amdgcn_mfma_f32_16x16x32_bf16(af[rt][0], d0, acc1, 0, 0, 0);
            acc1 = __builtin_amdgcn_mfma_f32_16x16x32_bf16(af[rt][1], d1, acc1, 0, 0, 0);
#pragma unroll
            for (int rg = 0; rg < 4; ++rg) {
                if (PASS == 0) {
                    // fmax(fmax) -> v_max3_f32: 1 VALU op per 2 scores
                    vmax[rt * 4 + rg] = fmaxf(vmax[rt * 4 + rg],
                                              fmaxf(acc0[rg], acc1[rg]));
                } else {
                    if (acc0[rg] >= nthr[rt * 4 + rg]) {
                        int pixel = pixbase + rg_id * 64 + rt * 16 + q * 4 + rg;
                        int code  = code0 + cg * 16 + c15;
                        u32 entry = ((u32)pixel << 13) | (u32)code;
                        u32 pos = atomicAdd(&loc_cnt, 1u);
                        if (pos < LOCBUF) loc_list[pos] = entry;
                        else { u32 g = atomicAdd(count, 1u);
                               if (g < CAP) list[g] = entry; }
                    }
                    if (acc1[rg] >= nthr[rt * 4 + rg]) {
                        int pixel = pixbase + rg_id * 64 + rt * 16 + q * 4 + rg;
                        int code  = code0 + (cg + 1) * 16 + c15;
                        u32 entry = ((u32)pixel << 13) | (u32)code;
                        u32 pos = atomicAdd(&loc_cnt, 1u);
                        if (pos < LOCBUF) loc_list[pos] = entry;
                        else { u32 g = atomicAdd(count, 1u);
                               if (g < CAP) list[g] = entry; }
                    }
                }
            }
        }
    }

    if (PASS == 0) {
        // Reduce the 16 code-columns per row, LDS-combine, plain store.
#pragma unroll
        for (int i = 0; i < 16; ++i) {
            float v = vmax[i];
            v = fmaxf(v, __shfl_xor(v, 1));
            v = fmaxf(v, __shfl_xor(v, 2));
            v = fmaxf(v, __shfl_xor(v, 4));
            v = fmaxf(v, __shfl_xor(v, 8));
            if (c15 == 0) {
                int row = rg_id * 64 + (i >> 2) * 16 + q * 4 + (i & 3);
                atomicMin(&cm_l[row], encf(-2.0f * v));   // LDS atomic, cheap
            }
        }
        __syncthreads();
        if (tid < M_BLK)
            cmin8[blockIdx.y * N_PIX + pixbase + tid] = cm_l[tid];
    } else {
        // Block-level flush: one global ticket, coalesced list writes.
        __syncthreads();
        u32 n_loc = loc_cnt; if (n_loc > LOCBUF) n_loc = LOCBUF;
        if (tid == 0) glob_base = atomicAdd(count, n_loc);
        __syncthreads();
        u32 base = glob_base;
        for (u32 i = tid; i < n_loc; i += 256u) {
            u32 g = base + i;
            if (g < CAP) list[g] = loc_list[i];
        }
    }
}

// Exact refine: bit-identical reference distance chain per candidate pair.
__global__ __launch_bounds__(256) void k_refine(const float* __restrict__ z,
                                                const float* __restrict__ emb,
                                                const float* __restrict__ Sarr,
                                                const float* __restrict__ Etab,
                                                const u32* __restrict__ count,
                                                const u32* __restrict__ list,
                                                u64* __restrict__ best) {
    u32 cnt = *count; if (cnt > CAP) cnt = CAP;
    for (u32 i = blockIdx.x * 256 + threadIdx.x; i < cnt; i += 256u * 256u) {
        u32 e = list[i];
        int pixel = (int)(e >> 13), code = (int)(e & 8191u);
        const float* zp = z + (pixel >> 12) * BHW + (pixel & 4095);
        const float* ep = emb + code * C_DIM;
        float dot = 0.0f;
#pragma unroll
        for (int c = 0; c < C_DIM; ++c)
            dot = __builtin_fmaf(zp[c * HW], ep[c], dot);
        float dist = __fsub_rn(__fadd_rn(Sarr[pixel], Etab[code]),
                               __fmul_rn(2.0f, dot));
        u64 key = ((u64)__float_as_uint(dist) << 32) | (u32)code;  // dist > 0
        atomicMin(&best[pixel], key);
    }
}

// Gather z_q, write idx + z_q_st (NCHW); f64 loss via global atomicAdd,
// last-finishing block (done-counter) writes out[0].
__global__ __launch_bounds__(256) void k_final(const float* __restrict__ z,
                                               const float* __restrict__ emb,
                                               const u64* __restrict__ best,
                                               float* __restrict__ out,
                                               double* __restrict__ loss_acc,
                                               u32* __restrict__ done) {
    const int n  = blockIdx.x * 256 + threadIdx.x;
    const int b  = n >> 12;
    const int hw = n & 4095;
    const u32 m  = (u32)(best[n] & 0xFFFFFFFFull);
    out[OUT_IDX_OFF + n] = (float)m;

    const float* zp = z + b * BHW + hw;
    const float* e  = emb + m * C_DIM;
    double lacc = 0.0;
#pragma unroll
    for (int c = 0; c < 64; ++c) {
        float zz   = zp[c * HW];
        float ec   = e[c];
        float diff = __fsub_rn(ec, zz);
        float outv = __fadd_rn(zz, diff);
        out[OUT_ZQ_OFF + b * BHW + c * HW + hw] = outv;
        lacc += (double)__fmul_rn(diff, diff);
    }
    __shared__ double sh[256];
    sh[threadIdx.x] = lacc;
    __syncthreads();
#pragma unroll
    for (int s = 128; s > 0; s >>= 1) {
        if (threadIdx.x < s) sh[threadIdx.x] += sh[threadIdx.x + s];
        __syncthreads();
    }
    if (threadIdx.x == 0) {
        atomicAdd(loss_acc, sh[0]);                 // device-scope f64 add
        __threadfence();
        u32 d = atomicAdd(done, 1u);
        if (d == (N_PIX / 256) - 1) {               // last block
            double s = atomicAdd(loss_acc, 0.0);    // atomic read of full sum
            float m1 = (float)(s / (double)ZQ_N);
            out[0] = __fadd_rn(m1, __fmul_rn(0.25f, m1));
        }
    }
}

extern "C" void kernel_launch(void* const* d_in, const int* in_sizes, int n_in,
                              void* d_out, int out_size, void* d_ws, size_t ws_size,
                              hipStream_t stream) {
    const float* z   = (const float*)d_in[0];
    const float* emb = (const float*)d_in[1];
    float* out = (float*)d_out;

    char* ws = (char*)d_ws;
    u64*    best  = (u64*)ws;
    float*  Etab  = (float*)(ws + WS_E_OFF);
    u32*    count = (u32*)(ws + WS_C_OFF);
    u32*    done  = (u32*)(ws + WS_D_OFF);
    double* lacc  = (double*)(ws + WS_A_OFF);

    float* SCR = out + 4;                       // 16B-aligned scratch in zq region
    u32*   zh    = (u32*)(SCR + OFF_ZH);
    u32*   eh    = (u32*)(SCR + OFF_EH);
    float* Sarr  = SCR + OFF_S;
    float* Wp    = SCR + OFF_W;
    u32*   cmin8 = (u32*)(SCR + OFF_CMIN8);
    u32*   list  = (u32*)(SCR + OFF_LIST);

    k_prep<<<dim3(N_PIX / 256 + NE / 256), dim3(256), 0, stream>>>(
        z, emb, zh, eh, Sarr, Wp, Etab, best, count, done, lacc);
    k_gemm<0><<<dim3(N_PIX / M_BLK, N_SLICES), dim3(256), 0, stream>>>(
        (const bf16x8*)zh, (const bf16x8*)eh, Wp, cmin8, count, list);
    k_gemm<1><<<dim3(N_PIX / M_BLK, N_SLICES), dim3(256), 0, stream>>>(
        (const bf16x8*)zh, (const bf16x8*)eh, Wp, cmin8, count, list);
    k_refine<<<dim3(256), dim3(256), 0, stream>>>(z, emb, Sarr, Etab, count, list, best);
    k_final <<<dim3(N_PIX / 256), dim3(256), 0, stream>>>(z, emb, best, out, lacc, done);
}